// Round 16
// baseline (195.137 us; speedup 1.0000x reference)
//
#include <hip/hip_runtime.h>
#include <math.h>

// GraphSAGE 2-layer + MLP head + softmax(2).
// CSR via bucketed counting sort; per layer {MFMA GEMM (t=X@Wl bf16,
// r=X@Wr+b f32), AGG (sigmoid(mean+r))}; wave-split register-weight MLP head.
// GEMM uses v_mfma_f32_16x16x32_bf16: A = X chunk (bf16, LDS), B = W^T
// (bf16, LDS, staged once per block), C/D f32.
// Uses mean linearity: mean(X[nbrs])@Wl == mean((X@Wl)[nbrs]).

#define NF1 48
#define HH 64
#define BKT_SHIFT 9
#define BKT_SZ (1 << BKT_SHIFT)
#define BCAP 9216  // per-bucket bins capacity; mean ~8192, std ~90 -> +11 sigma
#define EPB 16     // edges per thread in bin_edges

typedef __attribute__((ext_vector_type(8))) short short8v;   // 8 bf16 (4 VGPR)
typedef __attribute__((ext_vector_type(4))) float float4v;   // 4 f32 acc

__device__ __forceinline__ float sigmoidf_(float v) {
  return 1.0f / (1.0f + __expf(-v));
}
__device__ __forceinline__ float bflo(unsigned w) {
  union { unsigned u; float f; } c; c.u = w << 16; return c.f;
}
__device__ __forceinline__ float bfhi(unsigned w) {
  union { unsigned u; float f; } c; c.u = w & 0xffff0000u; return c.f;
}
__device__ __forceinline__ unsigned short f2bf(float f) {
  union { float f; unsigned u; } c; c.f = f;
  unsigned r = c.u + 0x7fffu + ((c.u >> 16) & 1u);  // RNE
  return (unsigned short)(r >> 16);
}

// Phase A: bin edges into per-bucket regions. bins[b*BCAP + pos] = (dl<<23|src).
__global__ __launch_bounds__(256) void bin_edges(
    const int* __restrict__ ei, int* __restrict__ cursor,
    unsigned* __restrict__ bins, int E, int NB) {
  __shared__ int hist[256];
  __shared__ int gbase[256];
  for (int i = threadIdx.x; i < NB; i += 256) hist[i] = 0;
  __syncthreads();
  int base_e = blockIdx.x * (256 * EPB) + threadIdx.x;
  unsigned pk[EPB];
  int bk[EPB], rk[EPB];
#pragma unroll
  for (int k = 0; k < EPB; k++) {
    int e = base_e + k * 256;
    bk[k] = -1;
    if (e < E) {
      int s = ei[e], d = ei[E + e];
      int b = d >> BKT_SHIFT;
      pk[k] = ((unsigned)(d & (BKT_SZ - 1)) << 23) | (unsigned)s;
      bk[k] = b;
      rk[k] = atomicAdd(&hist[b], 1);  // LDS atomic -> rank in (block,bucket)
    }
  }
  __syncthreads();
  for (int i = threadIdx.x; i < NB; i += 256) {
    int c = hist[i];
    gbase[i] = (c > 0) ? atomicAdd(&cursor[i], c) : 0;  // offset within bucket
  }
  __syncthreads();
#pragma unroll
  for (int k = 0; k < EPB; k++) {
    if (bk[k] >= 0) {
      int pos = gbase[bk[k]] + rk[k];
      bins[(size_t)bk[k] * BCAP + pos] = pk[k];
    }
  }
}

// Phase A2: exclusive scan of bucket counts (NB <= 256), base[NB] = E.
__global__ __launch_bounds__(256) void scan_buckets(
    const int* __restrict__ cursor, int* __restrict__ base, int NB) {
  __shared__ int a[256], b[256];
  int tid = threadIdx.x;
  int v = (tid < NB) ? cursor[tid] : 0;
  a[tid] = v;
  __syncthreads();
  int* s = a;
  int* d = b;
  for (int off = 1; off < 256; off <<= 1) {
    int t = s[tid] + ((tid >= off) ? s[tid - off] : 0);
    d[tid] = t;
    __syncthreads();
    int* tmp = s; s = d; d = tmp;
  }
  if (tid < NB) base[tid] = s[tid] - v;
  if (tid == NB - 1) base[NB] = s[tid];
}

// Phase B: one block per bucket. Local hist -> scan -> rp (coalesced) and
// csr scatter within the bucket's contiguous (L2-hot) window.
__global__ __launch_bounds__(512) void build_csr(
    const unsigned* __restrict__ bins, const int* __restrict__ cursor,
    const int* __restrict__ base,
    int* __restrict__ rp, int* __restrict__ csr, int n_nodes, int E, int NB) {
  __shared__ int hist[BKT_SZ];
  __shared__ int aa[BKT_SZ], bb[BKT_SZ];
  __shared__ int cur[BKT_SZ];
  int b = blockIdx.x;
  int tid = threadIdx.x;
  int node0 = b << BKT_SHIFT;
  int gb = base[b];
  int cnt = cursor[b];
  const unsigned* bp = bins + (size_t)b * BCAP;
  hist[tid] = 0;
  __syncthreads();
  for (int i = tid; i < cnt; i += 512) {
    atomicAdd(&hist[bp[i] >> 23], 1);
  }
  __syncthreads();
  int v = hist[tid];
  aa[tid] = v;
  __syncthreads();
  int* s = aa;
  int* d = bb;
  for (int off = 1; off < BKT_SZ; off <<= 1) {
    int t = s[tid] + ((tid >= off) ? s[tid - off] : 0);
    d[tid] = t;
    __syncthreads();
    int* tmp = s; s = d; d = tmp;
  }
  int loc = s[tid] - v;  // exclusive
  int node = node0 + tid;
  if (node < n_nodes) rp[node] = gb + loc;
  if (b == NB - 1 && tid == 0) rp[n_nodes] = E;
  cur[tid] = gb + loc;
  __syncthreads();
  for (int i = tid; i < cnt; i += 512) {
    unsigned p = bp[i];
    int dl = (int)(p >> 23);
    int pos = atomicAdd(&cur[dl], 1);
    csr[pos] = (int)(p & 0x7FFFFFu);
  }
}

// MFMA GEMM: t_out[n] = X[n]@Wl (bf16), r_out[n] = X[n]@Wr + bias (f32).
// 4 waves/block, 64-node chunk; wave wv owns row-tile [wv*16, wv*16+16),
// all 4 col-tiles, both matrices. A (X chunk) and B (W^T) staged bf16 in
// padded LDS [.][72] (2-way max bank aliasing = free).
// A-staging: float4 loads + packed uint2 LDS writes; zero-pad written once.
// Fragment layouts (v_mfma_f32_16x16x32_bf16):
//   A: row = lane&15, k = (lane>>4)*8 + i   (8 bf16, 1 ds_read_b128)
//   B: col = lane&15, k = (lane>>4)*8 + i   (from W^T rows, contiguous)
//   C/D: col = lane&15, row = (lane>>4)*4 + reg  [verified m89/m91]
template <int K>
__global__ __launch_bounds__(256, 4) void gemm_mfma(
    const float* __restrict__ X, const float* __restrict__ Wl,
    const float* __restrict__ Wr, const float* __restrict__ bias,
    unsigned short* __restrict__ t_out, float* __restrict__ r_out,
    int n_nodes) {
  __shared__ short sA[64][72];    // X chunk, bf16, k-padded to 64
  __shared__ short sWl[64][72];   // Wl^T: sWl[j][k]
  __shared__ short sWr[64][72];   // Wr^T
  int lane = threadIdx.x & 63, wv = threadIdx.x >> 6;
  int l15 = lane & 15, kq = lane >> 4;   // kq in 0..3

  // stage W^T (once per block), zero-fill k >= K
  for (int i = threadIdx.x; i < 64 * 64; i += 256) {
    int k = i >> 6, j = i & 63;
    short vl = 0, vr = 0;
    if (k < K) {
      vl = (short)f2bf(Wl[k * 64 + j]);
      vr = (short)f2bf(Wr[k * 64 + j]);
    }
    sWl[j][k] = vl;
    sWr[j][k] = vr;
  }
  // zero A's k-pad region once (never rewritten)
  if (K < 64) {
    constexpr int PADW = (64 - K) / 2;   // u32s per row
    for (int i = threadIdx.x; i < 64 * PADW; i += 256) {
      int row = i / PADW, p = i % PADW;
      *(unsigned*)&sA[row][K + 2 * p] = 0u;
    }
  }
  float bcol[4];
#pragma unroll
  for (int c = 0; c < 4; c++) bcol[c] = bias[c * 16 + l15];

  for (int nbase = blockIdx.x * 64; nbase < n_nodes; nbase += gridDim.x * 64) {
    __syncthreads();  // prev-iter LDS reads done / weights+pad staged
    // stage A: float4 loads, packed bf16 uint2 writes (8 B per item)
    for (int i = threadIdx.x; i < 64 * (K / 4); i += 256) {
      int row = i / (K / 4), c4 = i % (K / 4);
      int rr = nbase + row;
      if (rr >= n_nodes) rr = n_nodes - 1;
      float4 xv = ((const float4*)(X + (size_t)rr * K))[c4];
      unsigned lo = ((unsigned)f2bf(xv.y) << 16) | (unsigned)f2bf(xv.x);
      unsigned hi = ((unsigned)f2bf(xv.w) << 16) | (unsigned)f2bf(xv.z);
      uint2 pk = {lo, hi};
      *(uint2*)&sA[row][c4 * 4] = pk;
    }
    __syncthreads();

    float4v acc_t[4], acc_r[4];
#pragma unroll
    for (int c = 0; c < 4; c++) {
      acc_t[c] = (float4v){0.0f, 0.0f, 0.0f, 0.0f};
      acc_r[c] = (float4v){bcol[c], bcol[c], bcol[c], bcol[c]};
    }
#pragma unroll
    for (int s = 0; s < 2; s++) {
      short8v af = *(const short8v*)&sA[wv * 16 + l15][s * 32 + kq * 8];
#pragma unroll
      for (int c = 0; c < 4; c++) {
        short8v bl = *(const short8v*)&sWl[c * 16 + l15][s * 32 + kq * 8];
        short8v br = *(const short8v*)&sWr[c * 16 + l15][s * 32 + kq * 8];
        acc_t[c] = __builtin_amdgcn_mfma_f32_16x16x32_bf16(af, bl, acc_t[c], 0, 0, 0);
        acc_r[c] = __builtin_amdgcn_mfma_f32_16x16x32_bf16(af, br, acc_r[c], 0, 0, 0);
      }
    }

    // epilogue: node = nbase + wv*16 + kq*4 + g, col j = c*16 + l15
#pragma unroll
    for (int c = 0; c < 4; c++) {
      int j = c * 16 + l15;
#pragma unroll
      for (int g = 0; g < 4; g++) {
        int node = nbase + wv * 16 + kq * 4 + g;
        if (node < n_nodes) {
          t_out[(size_t)node * HH + j] = f2bf(acc_t[c][g]);
          r_out[(size_t)node * HH + j] = acc_r[c][g];
        }
      }
    }
  }
}

// h[n] = sigmoid(mean(t[nbrs(n)]) + r[n]); t bf16 rows, r/h f32 rows.
// One 16-lane group per node (16 nodes/block). Each lane owns 4 cols via
// uint2; 16-deep + 4-deep unrolled gather -> up to 16 load-instrs in
// flight per wave; no cross-lane reduction at all.
__global__ __launch_bounds__(256) void agg_sig(
    const unsigned short* __restrict__ t, const float* __restrict__ r,
    const int* __restrict__ rp, const int* __restrict__ csr,
    float* __restrict__ h, int n_nodes) {
  int grp = threadIdx.x >> 4;      // 0..15
  int q = threadIdx.x & 15;        // lane in group -> cols [4q, 4q+4)
  int node = blockIdx.x * 16 + grp;
  if (node >= n_nodes) return;
  int rs = rp[node], re = rp[node + 1];
  int deg = re - rs;
  const uint2* tb = (const uint2*)t + q;   // row i at tb[i*16]

  float a0 = 0, a1 = 0, a2 = 0, a3 = 0;
  int j = rs;
  for (; j + 15 < re; j += 16) {
    uint2 u[16];
#pragma unroll
    for (int k = 0; k < 16; k++) u[k] = tb[(size_t)csr[j + k] * 16];
#pragma unroll
    for (int k = 0; k < 16; k += 4) {
      a0 += (bflo(u[k].x) + bflo(u[k + 1].x)) + (bflo(u[k + 2].x) + bflo(u[k + 3].x));
      a1 += (bfhi(u[k].x) + bfhi(u[k + 1].x)) + (bfhi(u[k + 2].x) + bfhi(u[k + 3].x));
      a2 += (bflo(u[k].y) + bflo(u[k + 1].y)) + (bflo(u[k + 2].y) + bflo(u[k + 3].y));
      a3 += (bfhi(u[k].y) + bfhi(u[k + 1].y)) + (bfhi(u[k + 2].y) + bfhi(u[k + 3].y));
    }
  }
  for (; j + 3 < re; j += 4) {
    uint2 u0 = tb[(size_t)csr[j + 0] * 16];
    uint2 u1 = tb[(size_t)csr[j + 1] * 16];
    uint2 u2 = tb[(size_t)csr[j + 2] * 16];
    uint2 u3 = tb[(size_t)csr[j + 3] * 16];
    a0 += (bflo(u0.x) + bflo(u1.x)) + (bflo(u2.x) + bflo(u3.x));
    a1 += (bfhi(u0.x) + bfhi(u1.x)) + (bfhi(u2.x) + bfhi(u3.x));
    a2 += (bflo(u0.y) + bflo(u1.y)) + (bflo(u2.y) + bflo(u3.y));
    a3 += (bfhi(u0.y) + bfhi(u1.y)) + (bfhi(u2.y) + bfhi(u3.y));
  }
  for (; j < re; j++) {
    uint2 u = tb[(size_t)csr[j] * 16];
    a0 += bflo(u.x);
    a1 += bfhi(u.x);
    a2 += bflo(u.y);
    a3 += bfhi(u.y);
  }

  float inv = 1.0f / fmaxf((float)deg, 1.0f);
  float4 rv = ((const float4*)(r + (size_t)node * HH))[q];
  float4 o;
  o.x = sigmoidf_(a0 * inv + rv.x);
  o.y = sigmoidf_(a1 * inv + rv.y);
  o.z = sigmoidf_(a2 * inv + rv.z);
  o.w = sigmoidf_(a3 * inv + rv.w);
  ((float4*)(h + (size_t)node * HH))[q] = o;
}

// MLP head: h3 = sigmoid(h2 @ Wlin1 + blin1); out = softmax(h3 @ Wlin2 + blin2).
// 8 waves, 64-node chunk; lane holds Wlin1 column in registers (64 VGPR).
// h3 goes to LDS; logits via transposed reduce: 8 threads/node, 3-step shfl.
__global__ __launch_bounds__(512, 4) void head_k(
    const float* __restrict__ h2,
    const float* __restrict__ Wlin1, const float* __restrict__ blin1,
    const float* __restrict__ Wlin2, const float* __restrict__ blin2,
    float* __restrict__ out, int n_nodes) {
  __shared__ float sx[64][HH];    // 64-node chunk input
  __shared__ float sh3[64][HH];   // h3 values
  __shared__ float sw2[HH * 2];
  int wv = threadIdx.x >> 6, lane = threadIdx.x & 63;

  float w1[HH];
#pragma unroll
  for (int k = 0; k < HH; k++) w1[k] = Wlin1[k * HH + lane];
  float bv = blin1[lane];
  if (threadIdx.x < HH * 2) sw2[threadIdx.x] = Wlin2[threadIdx.x];
  float sb20 = blin2[0], sb21 = blin2[1];

  for (int nbase = blockIdx.x * 64; nbase < n_nodes; nbase += gridDim.x * 64) {
    __syncthreads();  // prev-iter sx/sh3 reads done
    for (int i = threadIdx.x; i < 64 * (HH / 4); i += 512) {
      int row = i >> 4, c4 = i & 15;
      int rr = nbase + row;
      if (rr >= n_nodes) rr = n_nodes - 1;
      ((float4*)sx[row])[c4] = ((const float4*)(h2 + (size_t)rr * HH))[c4];
    }
    __syncthreads();

    float acc[8];
#pragma unroll
    for (int m = 0; m < 8; m++) acc[m] = bv;
#pragma unroll
    for (int k = 0; k < HH; k += 4) {
#pragma unroll
      for (int m = 0; m < 8; m++) {
        float4 a = *(const float4*)&sx[wv * 8 + m][k];
        acc[m] += a.x * w1[k] + a.y * w1[k + 1] + a.z * w1[k + 2] + a.w * w1[k + 3];
      }
    }
#pragma unroll
    for (int m = 0; m < 8; m++) sh3[wv * 8 + m][lane] = sigmoidf_(acc[m]);
    __syncthreads();

    // transposed logit reduce: 8 threads per node, 8 cols each
    int node_l = threadIdx.x >> 3;   // 0..63
    int sub = threadIdx.x & 7;
    float l0 = 0.0f, l1 = 0.0f;
#pragma unroll
    for (int kk = 0; kk < 8; kk++) {
      int k = sub * 8 + kk;
      float v = sh3[node_l][k];
      l0 += v * sw2[k * 2 + 0];
      l1 += v * sw2[k * 2 + 1];
    }
    l0 += __shfl_xor(l0, 1); l1 += __shfl_xor(l1, 1);
    l0 += __shfl_xor(l0, 2); l1 += __shfl_xor(l1, 2);
    l0 += __shfl_xor(l0, 4); l1 += __shfl_xor(l1, 4);
    int node = nbase + node_l;
    if (sub == 0 && node < n_nodes) {
      l0 += sb20;
      l1 += sb21;
      float mx = fmaxf(l0, l1);
      float p0 = __expf(l0 - mx), p1 = __expf(l1 - mx);
      float s = 1.0f / (p0 + p1);
      float2 o2 = {p0 * s, p1 * s};
      ((float2*)out)[node] = o2;
    }
  }
}

extern "C" void kernel_launch(void* const* d_in, const int* in_sizes, int n_in,
                              void* d_out, int out_size, void* d_ws, size_t ws_size,
                              hipStream_t stream) {
  const float* x     = (const float*)d_in[0];
  const int*   ei    = (const int*)d_in[1];
  const float* W1l   = (const float*)d_in[2];
  const float* b1l   = (const float*)d_in[3];
  const float* W1r   = (const float*)d_in[4];
  const float* W2l   = (const float*)d_in[5];
  const float* b2l   = (const float*)d_in[6];
  const float* W2r   = (const float*)d_in[7];
  const float* Wlin1 = (const float*)d_in[8];
  const float* blin1 = (const float*)d_in[9];
  const float* Wlin2 = (const float*)d_in[10];
  const float* blin2 = (const float*)d_in[11];
  float* out = (float*)d_out;

  int n = in_sizes[0] / NF1;
  int E = in_sizes[1] / 2;
  int NB = (n + BKT_SZ - 1) >> BKT_SHIFT;  // 196 for this problem (<= 256)

  int* base   = (int*)d_ws;                 // [NB+1]
  int* cursor = base + NB + 1;              // [NB]
  int* rp     = cursor + NB;                // [n+1]
  int* csr    = rp + n + 1;                 // [E]
  size_t off = (size_t)(NB + 1 + NB + n + 1 + E) * sizeof(int);
  off = (off + 255) & ~(size_t)255;
  unsigned* bins = (unsigned*)((char*)d_ws + off);  // [NB*BCAP] u32 (dead after CSR)
  // tbuf aliases bins: n*64*2 = 12.8MB >= NB*BCAP*4 = 7.2MB, used only after build
  unsigned short* tbuf = (unsigned short*)bins;     // [n,64] bf16
  size_t reg = (size_t)NB * BCAP * sizeof(unsigned);
  size_t treg = (size_t)n * HH * sizeof(unsigned short);
  off += (reg > treg ? reg : treg);
  off = (off + 255) & ~(size_t)255;
  float* rbuf = (float*)((char*)d_ws + off);  // [n,64] f32
  off += (size_t)n * HH * sizeof(float);
  off = (off + 255) & ~(size_t)255;
  float* hbuf = (float*)((char*)d_ws + off);  // [n,64] f32 (h1, then h2)

  hipMemsetAsync(cursor, 0, (size_t)NB * sizeof(int), stream);

  int abk = (E + 256 * EPB - 1) / (256 * EPB);
  bin_edges<<<abk, 256, 0, stream>>>(ei, cursor, bins, E, NB);
  scan_buckets<<<1, 256, 0, stream>>>(cursor, base, NB);
  build_csr<<<NB, 512, 0, stream>>>(bins, cursor, base, rp, csr, n, E, NB);

  int chunks = (n + 63) / 64;
  int gemmb = chunks < 1024 ? chunks : 1024;
  int aggb = (n + 15) / 16;
  int headb = (n + 63) / 64;
  if (headb > 1024) headb = 1024;

  // layer 1: t = x@W1l (bf16), r = x@W1r + b1l; h1 = sigmoid(mean(t)+r)
  gemm_mfma<NF1><<<gemmb, 256, 0, stream>>>(x, W1l, W1r, b1l, tbuf, rbuf, n);
  agg_sig<<<aggb, 256, 0, stream>>>(tbuf, rbuf, rp, csr, hbuf, n);

  // layer 2: t = h1@W2l (bf16), r = h1@W2r + b2l; h2 = sigmoid(mean(t)+r)
  gemm_mfma<HH><<<gemmb, 256, 0, stream>>>(hbuf, W2l, W2r, b2l, tbuf, rbuf, n);
  agg_sig<<<aggb, 256, 0, stream>>>(tbuf, rbuf, rp, csr, hbuf, n);

  // MLP head (wave-split register weights + transposed logit reduce)
  head_k<<<headb, 512, 0, stream>>>(hbuf, Wlin1, blin1, Wlin2, blin2, out, n);
}

// Round 17
// 181.284 us; speedup vs baseline: 1.0764x; 1.0764x over previous
//
#include <hip/hip_runtime.h>
#include <math.h>

// GraphSAGE 2-layer + MLP head + softmax(2).
// CSR via bucketed counting sort (256-node buckets); per layer {MFMA GEMM
// (t=X@Wl bf16, r=X@Wr+b f32), AGG (sigmoid(mean+r))}; register-weight head.
// Uses mean linearity: mean(X[nbrs])@Wl == mean((X@Wl)[nbrs]).

#define NF1 48
#define HH 64
#define BKT_SHIFT 8
#define BKT_SZ (1 << BKT_SHIFT)   // 256
#define BCAP 4800  // per-bucket capacity; mean ~4092, std ~64 -> +11 sigma
#define EPB 16     // edges per thread in bin_edges

typedef __attribute__((ext_vector_type(8))) short short8v;   // 8 bf16 (4 VGPR)
typedef __attribute__((ext_vector_type(4))) float float4v;   // 4 f32 acc

__device__ __forceinline__ float sigmoidf_(float v) {
  return 1.0f / (1.0f + __expf(-v));
}
__device__ __forceinline__ float bflo(unsigned w) {
  union { unsigned u; float f; } c; c.u = w << 16; return c.f;
}
__device__ __forceinline__ float bfhi(unsigned w) {
  union { unsigned u; float f; } c; c.u = w & 0xffff0000u; return c.f;
}
__device__ __forceinline__ unsigned short f2bf(float f) {
  union { float f; unsigned u; } c; c.f = f;
  unsigned r = c.u + 0x7fffu + ((c.u >> 16) & 1u);  // RNE
  return (unsigned short)(r >> 16);
}

// Phase A: bin edges into per-bucket regions. bins[b*BCAP + pos] = (dl<<23|src).
__global__ __launch_bounds__(256) void bin_edges(
    const int* __restrict__ ei, int* __restrict__ cursor,
    unsigned* __restrict__ bins, int E, int NB) {
  __shared__ int hist[512];
  __shared__ int gbase[512];
  for (int i = threadIdx.x; i < NB; i += 256) hist[i] = 0;
  __syncthreads();
  int base_e = blockIdx.x * (256 * EPB) + threadIdx.x;
  unsigned pk[EPB];
  int bk[EPB], rk[EPB];
#pragma unroll
  for (int k = 0; k < EPB; k++) {
    int e = base_e + k * 256;
    bk[k] = -1;
    if (e < E) {
      int s = ei[e], d = ei[E + e];
      int b = d >> BKT_SHIFT;
      pk[k] = ((unsigned)(d & (BKT_SZ - 1)) << 23) | (unsigned)s;
      bk[k] = b;
      rk[k] = atomicAdd(&hist[b], 1);  // LDS atomic -> rank in (block,bucket)
    }
  }
  __syncthreads();
  for (int i = threadIdx.x; i < NB; i += 256) {
    int c = hist[i];
    gbase[i] = (c > 0) ? atomicAdd(&cursor[i], c) : 0;  // offset within bucket
  }
  __syncthreads();
#pragma unroll
  for (int k = 0; k < EPB; k++) {
    if (bk[k] >= 0) {
      int pos = gbase[bk[k]] + rk[k];
      bins[(size_t)bk[k] * BCAP + pos] = pk[k];
    }
  }
}

// Phase A2: exclusive scan of bucket counts (NB <= 512), base[NB] = E.
__global__ __launch_bounds__(512) void scan_buckets(
    const int* __restrict__ cursor, int* __restrict__ base, int NB) {
  __shared__ int a[512], b[512];
  int tid = threadIdx.x;
  int v = (tid < NB) ? cursor[tid] : 0;
  a[tid] = v;
  __syncthreads();
  int* s = a;
  int* d = b;
  for (int off = 1; off < 512; off <<= 1) {
    int t = s[tid] + ((tid >= off) ? s[tid - off] : 0);
    d[tid] = t;
    __syncthreads();
    int* tmp = s; s = d; d = tmp;
  }
  if (tid < NB) base[tid] = s[tid] - v;
  if (tid == NB - 1) base[NB] = s[tid];
}

// Phase B: one 256-thread block per bucket. Local hist -> scan -> rp and
// csr scatter within the bucket's contiguous (L2-hot) window.
__global__ __launch_bounds__(256) void build_csr(
    const unsigned* __restrict__ bins, const int* __restrict__ cursor,
    const int* __restrict__ base,
    int* __restrict__ rp, int* __restrict__ csr, int n_nodes, int E, int NB) {
  __shared__ int hist[BKT_SZ];
  __shared__ int aa[BKT_SZ], bb[BKT_SZ];
  __shared__ int cur[BKT_SZ];
  int b = blockIdx.x;
  int tid = threadIdx.x;
  int node0 = b << BKT_SHIFT;
  int gb = base[b];
  int cnt = cursor[b];
  const unsigned* bp = bins + (size_t)b * BCAP;
  hist[tid] = 0;
  __syncthreads();
  for (int i = tid; i < cnt; i += 256) {
    atomicAdd(&hist[bp[i] >> 23], 1);
  }
  __syncthreads();
  int v = hist[tid];
  aa[tid] = v;
  __syncthreads();
  int* s = aa;
  int* d = bb;
  for (int off = 1; off < BKT_SZ; off <<= 1) {
    int t = s[tid] + ((tid >= off) ? s[tid - off] : 0);
    d[tid] = t;
    __syncthreads();
    int* tmp = s; s = d; d = tmp;
  }
  int loc = s[tid] - v;  // exclusive
  int node = node0 + tid;
  if (node < n_nodes) rp[node] = gb + loc;
  if (b == NB - 1 && tid == 0) rp[n_nodes] = E;
  cur[tid] = gb + loc;
  __syncthreads();
  for (int i = tid; i < cnt; i += 256) {
    unsigned p = bp[i];
    int dl = (int)(p >> 23);
    int pos = atomicAdd(&cur[dl], 1);
    csr[pos] = (int)(p & 0x7FFFFFu);
  }
}

// MFMA GEMM: t_out[n] = X[n]@Wl (bf16), r_out[n] = X[n]@Wr + bias (f32).
// 4 waves/block, 64-node chunk; wave wv owns row-tile [wv*16, wv*16+16),
// all 4 col-tiles, both matrices. A (X chunk) and B (W^T) staged bf16 in
// padded LDS [.][72] (2-way max bank aliasing = free).
// Fragment layouts (v_mfma_f32_16x16x32_bf16):
//   A: row = lane&15, k = (lane>>4)*8 + i   (8 bf16, 1 ds_read_b128)
//   B: col = lane&15, k = (lane>>4)*8 + i   (from W^T rows, contiguous)
//   C/D: col = lane&15, row = (lane>>4)*4 + reg  [verified m89/m91]
template <int K>
__global__ __launch_bounds__(256, 4) void gemm_mfma(
    const float* __restrict__ X, const float* __restrict__ Wl,
    const float* __restrict__ Wr, const float* __restrict__ bias,
    unsigned short* __restrict__ t_out, float* __restrict__ r_out,
    int n_nodes) {
  __shared__ short sA[64][72];    // X chunk, bf16, k-padded to 64
  __shared__ short sWl[64][72];   // Wl^T: sWl[j][k]
  __shared__ short sWr[64][72];   // Wr^T
  int lane = threadIdx.x & 63, wv = threadIdx.x >> 6;
  int l15 = lane & 15, kq = lane >> 4;   // kq in 0..3

  // stage W^T (once per block), zero-fill k >= K
  for (int i = threadIdx.x; i < 64 * 64; i += 256) {
    int k = i >> 6, j = i & 63;
    short vl = 0, vr = 0;
    if (k < K) {
      vl = (short)f2bf(Wl[k * 64 + j]);
      vr = (short)f2bf(Wr[k * 64 + j]);
    }
    sWl[j][k] = vl;
    sWr[j][k] = vr;
  }
  // zero A's k-pad region once (never rewritten)
  if (K < 64) {
    constexpr int PADW = (64 - K) / 2;   // u32s per row
    for (int i = threadIdx.x; i < 64 * PADW; i += 256) {
      int row = i / PADW, p = i % PADW;
      *(unsigned*)&sA[row][K + 2 * p] = 0u;
    }
  }
  float bcol[4];
#pragma unroll
  for (int c = 0; c < 4; c++) bcol[c] = bias[c * 16 + l15];

  for (int nbase = blockIdx.x * 64; nbase < n_nodes; nbase += gridDim.x * 64) {
    __syncthreads();  // prev-iter LDS reads done / weights+pad staged
    // stage A: float4 loads, packed bf16 uint2 writes (8 B per item)
    for (int i = threadIdx.x; i < 64 * (K / 4); i += 256) {
      int row = i / (K / 4), c4 = i % (K / 4);
      int rr = nbase + row;
      if (rr >= n_nodes) rr = n_nodes - 1;
      float4 xv = ((const float4*)(X + (size_t)rr * K))[c4];
      unsigned lo = ((unsigned)f2bf(xv.y) << 16) | (unsigned)f2bf(xv.x);
      unsigned hi = ((unsigned)f2bf(xv.w) << 16) | (unsigned)f2bf(xv.z);
      uint2 pk = {lo, hi};
      *(uint2*)&sA[row][c4 * 4] = pk;
    }
    __syncthreads();

    float4v acc_t[4], acc_r[4];
#pragma unroll
    for (int c = 0; c < 4; c++) {
      acc_t[c] = (float4v){0.0f, 0.0f, 0.0f, 0.0f};
      acc_r[c] = (float4v){bcol[c], bcol[c], bcol[c], bcol[c]};
    }
#pragma unroll
    for (int s = 0; s < 2; s++) {
      short8v af = *(const short8v*)&sA[wv * 16 + l15][s * 32 + kq * 8];
#pragma unroll
      for (int c = 0; c < 4; c++) {
        short8v bl = *(const short8v*)&sWl[c * 16 + l15][s * 32 + kq * 8];
        short8v br = *(const short8v*)&sWr[c * 16 + l15][s * 32 + kq * 8];
        acc_t[c] = __builtin_amdgcn_mfma_f32_16x16x32_bf16(af, bl, acc_t[c], 0, 0, 0);
        acc_r[c] = __builtin_amdgcn_mfma_f32_16x16x32_bf16(af, br, acc_r[c], 0, 0, 0);
      }
    }

    // epilogue: node = nbase + wv*16 + kq*4 + g, col j = c*16 + l15
#pragma unroll
    for (int c = 0; c < 4; c++) {
      int j = c * 16 + l15;
#pragma unroll
      for (int g = 0; g < 4; g++) {
        int node = nbase + wv * 16 + kq * 4 + g;
        if (node < n_nodes) {
          t_out[(size_t)node * HH + j] = f2bf(acc_t[c][g]);
          r_out[(size_t)node * HH + j] = acc_r[c][g];
        }
      }
    }
  }
}

// h[n] = sigmoid(mean(t[nbrs(n)]) + r[n]); t bf16 rows, r/h f32 rows.
// One 16-lane group per node (16 nodes/block). Each lane owns 4 cols via
// uint2; 8-deep + 4-deep unrolled gather; no cross-lane reduction at all.
__global__ __launch_bounds__(256) void agg_sig(
    const unsigned short* __restrict__ t, const float* __restrict__ r,
    const int* __restrict__ rp, const int* __restrict__ csr,
    float* __restrict__ h, int n_nodes) {
  int grp = threadIdx.x >> 4;      // 0..15
  int q = threadIdx.x & 15;        // lane in group -> cols [4q, 4q+4)
  int node = blockIdx.x * 16 + grp;
  if (node >= n_nodes) return;
  int rs = rp[node], re = rp[node + 1];
  int deg = re - rs;
  const uint2* tb = (const uint2*)t + q;   // row i at tb[i*16]

  float a0 = 0, a1 = 0, a2 = 0, a3 = 0;
  int j = rs;
  for (; j + 7 < re; j += 8) {
    uint2 u0 = tb[(size_t)csr[j + 0] * 16];
    uint2 u1 = tb[(size_t)csr[j + 1] * 16];
    uint2 u2 = tb[(size_t)csr[j + 2] * 16];
    uint2 u3 = tb[(size_t)csr[j + 3] * 16];
    uint2 u4 = tb[(size_t)csr[j + 4] * 16];
    uint2 u5 = tb[(size_t)csr[j + 5] * 16];
    uint2 u6 = tb[(size_t)csr[j + 6] * 16];
    uint2 u7 = tb[(size_t)csr[j + 7] * 16];
    a0 += ((bflo(u0.x) + bflo(u1.x)) + (bflo(u2.x) + bflo(u3.x))) +
          ((bflo(u4.x) + bflo(u5.x)) + (bflo(u6.x) + bflo(u7.x)));
    a1 += ((bfhi(u0.x) + bfhi(u1.x)) + (bfhi(u2.x) + bfhi(u3.x))) +
          ((bfhi(u4.x) + bfhi(u5.x)) + (bfhi(u6.x) + bfhi(u7.x)));
    a2 += ((bflo(u0.y) + bflo(u1.y)) + (bflo(u2.y) + bflo(u3.y))) +
          ((bflo(u4.y) + bflo(u5.y)) + (bflo(u6.y) + bflo(u7.y)));
    a3 += ((bfhi(u0.y) + bfhi(u1.y)) + (bfhi(u2.y) + bfhi(u3.y))) +
          ((bfhi(u4.y) + bfhi(u5.y)) + (bfhi(u6.y) + bfhi(u7.y)));
  }
  if (j + 3 < re) {
    uint2 u0 = tb[(size_t)csr[j + 0] * 16];
    uint2 u1 = tb[(size_t)csr[j + 1] * 16];
    uint2 u2 = tb[(size_t)csr[j + 2] * 16];
    uint2 u3 = tb[(size_t)csr[j + 3] * 16];
    a0 += (bflo(u0.x) + bflo(u1.x)) + (bflo(u2.x) + bflo(u3.x));
    a1 += (bfhi(u0.x) + bfhi(u1.x)) + (bfhi(u2.x) + bfhi(u3.x));
    a2 += (bflo(u0.y) + bflo(u1.y)) + (bflo(u2.y) + bflo(u3.y));
    a3 += (bfhi(u0.y) + bfhi(u1.y)) + (bfhi(u2.y) + bfhi(u3.y));
    j += 4;
  }
  for (; j < re; j++) {
    uint2 u = tb[(size_t)csr[j] * 16];
    a0 += bflo(u.x);
    a1 += bfhi(u.x);
    a2 += bflo(u.y);
    a3 += bfhi(u.y);
  }

  float inv = 1.0f / fmaxf((float)deg, 1.0f);
  float4 rv = ((const float4*)(r + (size_t)node * HH))[q];
  float4 o;
  o.x = sigmoidf_(a0 * inv + rv.x);
  o.y = sigmoidf_(a1 * inv + rv.y);
  o.z = sigmoidf_(a2 * inv + rv.z);
  o.w = sigmoidf_(a3 * inv + rv.w);
  ((float4*)(h + (size_t)node * HH))[q] = o;
}

// MLP head: h3 = sigmoid(h2 @ Wlin1 + blin1); out = softmax(h3 @ Wlin2 + blin2).
// 8 waves, 64-node chunk; lane holds Wlin1 column in registers (64 VGPR).
// h3 goes to LDS; logits via transposed reduce: 8 threads/node, 3-step shfl.
__global__ __launch_bounds__(512, 4) void head_k(
    const float* __restrict__ h2,
    const float* __restrict__ Wlin1, const float* __restrict__ blin1,
    const float* __restrict__ Wlin2, const float* __restrict__ blin2,
    float* __restrict__ out, int n_nodes) {
  __shared__ float sx[64][HH];    // 64-node chunk input
  __shared__ float sh3[64][HH];   // h3 values
  __shared__ float sw2[HH * 2];
  int wv = threadIdx.x >> 6, lane = threadIdx.x & 63;

  float w1[HH];
#pragma unroll
  for (int k = 0; k < HH; k++) w1[k] = Wlin1[k * HH + lane];
  float bv = blin1[lane];
  if (threadIdx.x < HH * 2) sw2[threadIdx.x] = Wlin2[threadIdx.x];
  float sb20 = blin2[0], sb21 = blin2[1];

  for (int nbase = blockIdx.x * 64; nbase < n_nodes; nbase += gridDim.x * 64) {
    __syncthreads();  // prev-iter sx/sh3 reads done
    for (int i = threadIdx.x; i < 64 * (HH / 4); i += 512) {
      int row = i >> 4, c4 = i & 15;
      int rr = nbase + row;
      if (rr >= n_nodes) rr = n_nodes - 1;
      ((float4*)sx[row])[c4] = ((const float4*)(h2 + (size_t)rr * HH))[c4];
    }
    __syncthreads();

    float acc[8];
#pragma unroll
    for (int m = 0; m < 8; m++) acc[m] = bv;
#pragma unroll
    for (int k = 0; k < HH; k += 4) {
#pragma unroll
      for (int m = 0; m < 8; m++) {
        float4 a = *(const float4*)&sx[wv * 8 + m][k];
        acc[m] += a.x * w1[k] + a.y * w1[k + 1] + a.z * w1[k + 2] + a.w * w1[k + 3];
      }
    }
#pragma unroll
    for (int m = 0; m < 8; m++) sh3[wv * 8 + m][lane] = sigmoidf_(acc[m]);
    __syncthreads();

    // transposed logit reduce: 8 threads per node, 8 cols each
    int node_l = threadIdx.x >> 3;   // 0..63
    int sub = threadIdx.x & 7;
    float l0 = 0.0f, l1 = 0.0f;
#pragma unroll
    for (int kk = 0; kk < 8; kk++) {
      int k = sub * 8 + kk;
      float v = sh3[node_l][k];
      l0 += v * sw2[k * 2 + 0];
      l1 += v * sw2[k * 2 + 1];
    }
    l0 += __shfl_xor(l0, 1); l1 += __shfl_xor(l1, 1);
    l0 += __shfl_xor(l0, 2); l1 += __shfl_xor(l1, 2);
    l0 += __shfl_xor(l0, 4); l1 += __shfl_xor(l1, 4);
    int node = nbase + node_l;
    if (sub == 0 && node < n_nodes) {
      l0 += sb20;
      l1 += sb21;
      float mx = fmaxf(l0, l1);
      float p0 = __expf(l0 - mx), p1 = __expf(l1 - mx);
      float s = 1.0f / (p0 + p1);
      float2 o2 = {p0 * s, p1 * s};
      ((float2*)out)[node] = o2;
    }
  }
}

extern "C" void kernel_launch(void* const* d_in, const int* in_sizes, int n_in,
                              void* d_out, int out_size, void* d_ws, size_t ws_size,
                              hipStream_t stream) {
  const float* x     = (const float*)d_in[0];
  const int*   ei    = (const int*)d_in[1];
  const float* W1l   = (const float*)d_in[2];
  const float* b1l   = (const float*)d_in[3];
  const float* W1r   = (const float*)d_in[4];
  const float* W2l   = (const float*)d_in[5];
  const float* b2l   = (const float*)d_in[6];
  const float* W2r   = (const float*)d_in[7];
  const float* Wlin1 = (const float*)d_in[8];
  const float* blin1 = (const float*)d_in[9];
  const float* Wlin2 = (const float*)d_in[10];
  const float* blin2 = (const float*)d_in[11];
  float* out = (float*)d_out;

  int n = in_sizes[0] / NF1;
  int E = in_sizes[1] / 2;
  int NB = (n + BKT_SZ - 1) >> BKT_SHIFT;  // 391 for this problem (<= 512)

  int* base   = (int*)d_ws;                 // [NB+1]
  int* cursor = base + NB + 1;              // [NB]
  int* rp     = cursor + NB;                // [n+1]
  int* csr    = rp + n + 1;                 // [E]
  size_t off = (size_t)(NB + 1 + NB + n + 1 + E) * sizeof(int);
  off = (off + 255) & ~(size_t)255;
  unsigned* bins = (unsigned*)((char*)d_ws + off);  // [NB*BCAP] u32 (dead after CSR)
  // tbuf aliases bins: n*64*2 = 12.8MB >= NB*BCAP*4 = 7.5MB, used only after build
  unsigned short* tbuf = (unsigned short*)bins;     // [n,64] bf16
  size_t reg = (size_t)NB * BCAP * sizeof(unsigned);
  size_t treg = (size_t)n * HH * sizeof(unsigned short);
  off += (reg > treg ? reg : treg);
  off = (off + 255) & ~(size_t)255;
  float* rbuf = (float*)((char*)d_ws + off);  // [n,64] f32
  off += (size_t)n * HH * sizeof(float);
  off = (off + 255) & ~(size_t)255;
  float* hbuf = (float*)((char*)d_ws + off);  // [n,64] f32 (h1, then h2)

  hipMemsetAsync(cursor, 0, (size_t)NB * sizeof(int), stream);

  int abk = (E + 256 * EPB - 1) / (256 * EPB);
  bin_edges<<<abk, 256, 0, stream>>>(ei, cursor, bins, E, NB);
  scan_buckets<<<1, 512, 0, stream>>>(cursor, base, NB);
  build_csr<<<NB, 256, 0, stream>>>(bins, cursor, base, rp, csr, n, E, NB);

  int chunks = (n + 63) / 64;
  int gemmb = chunks < 1024 ? chunks : 1024;
  int aggb = (n + 15) / 16;
  int headb = (n + 63) / 64;
  if (headb > 1024) headb = 1024;

  // layer 1: t = x@W1l (bf16), r = x@W1r + b1l; h1 = sigmoid(mean(t)+r)
  gemm_mfma<NF1><<<gemmb, 256, 0, stream>>>(x, W1l, W1r, b1l, tbuf, rbuf, n);
  agg_sig<<<aggb, 256, 0, stream>>>(tbuf, rbuf, rp, csr, hbuf, n);

  // layer 2: t = h1@W2l (bf16), r = h1@W2r + b2l; h2 = sigmoid(mean(t)+r)
  gemm_mfma<HH><<<gemmb, 256, 0, stream>>>(hbuf, W2l, W2r, b2l, tbuf, rbuf, n);
  agg_sig<<<aggb, 256, 0, stream>>>(tbuf, rbuf, rp, csr, hbuf, n);

  // MLP head (wave-split register weights + transposed logit reduce)
  head_k<<<headb, 512, 0, stream>>>(hbuf, Wlin1, blin1, Wlin2, blin2, out, n);
}

// Round 18
// 170.471 us; speedup vs baseline: 1.1447x; 1.0634x over previous
//
#include <hip/hip_runtime.h>
#include <math.h>

// GraphSAGE 2-layer + MLP head + softmax(2).
// Schedule: memset -> [fused: bin_edges || gemm1] -> build_csr(+inline scan)
// -> agg1 -> gemm2 -> agg2 -> head.
// bins aliases hbuf (first written by agg1, after build_csr) so binning can
// run concurrently with gemm1 (which writes tbuf/rbuf).
// Uses mean linearity: mean(X[nbrs])@Wl == mean((X@Wl)[nbrs]).

#define NF1 48
#define HH 64
#define BKT_SHIFT 8
#define BKT_SZ (1 << BKT_SHIFT)   // 256
#define BCAP 4800  // per-bucket capacity; mean ~4092, std ~64 -> +11 sigma
#define EPB 16     // edges per thread in bin phase

typedef __attribute__((ext_vector_type(8))) short short8v;   // 8 bf16 (4 VGPR)
typedef __attribute__((ext_vector_type(4))) float float4v;   // 4 f32 acc

__device__ __forceinline__ float sigmoidf_(float v) {
  return 1.0f / (1.0f + __expf(-v));
}
__device__ __forceinline__ float bflo(unsigned w) {
  union { unsigned u; float f; } c; c.u = w << 16; return c.f;
}
__device__ __forceinline__ float bfhi(unsigned w) {
  union { unsigned u; float f; } c; c.u = w & 0xffff0000u; return c.f;
}
__device__ __forceinline__ unsigned short f2bf(float f) {
  union { float f; unsigned u; } c; c.f = f;
  unsigned r = c.u + 0x7fffu + ((c.u >> 16) & 1u);  // RNE
  return (unsigned short)(r >> 16);
}

// Fused kernel: blocks [0, abk) bin edges into per-bucket regions;
// blocks [abk, abk+gemmb) run the layer-1 MFMA GEMM.
// LDS is a raw arena reinterpreted per path.
template <int K>
__global__ __launch_bounds__(256, 4) void fused_bin_gemm(
    const int* __restrict__ ei, int* __restrict__ cursor,
    unsigned* __restrict__ bins, int E, int NB,
    const float* __restrict__ X, const float* __restrict__ Wl,
    const float* __restrict__ Wr, const float* __restrict__ bias,
    unsigned short* __restrict__ t_out, float* __restrict__ r_out,
    int n_nodes, int abk, int gemmb) {
  __shared__ __align__(16) char smem[3 * 64 * 72 * 2];  // 27648 B arena

  if ((int)blockIdx.x < abk) {
    // ---- bin_edges path ----
    int* hist = (int*)smem;          // [512]
    int* gbase = hist + 512;         // [512]
    for (int i = threadIdx.x; i < NB; i += 256) hist[i] = 0;
    __syncthreads();
    int base_e = blockIdx.x * (256 * EPB) + threadIdx.x;
    unsigned pk[EPB];
    int bk[EPB], rk[EPB];
#pragma unroll
    for (int k = 0; k < EPB; k++) {
      int e = base_e + k * 256;
      bk[k] = -1;
      if (e < E) {
        int s = ei[e], d = ei[E + e];
        int b = d >> BKT_SHIFT;
        pk[k] = ((unsigned)(d & (BKT_SZ - 1)) << 23) | (unsigned)s;
        bk[k] = b;
        rk[k] = atomicAdd(&hist[b], 1);
      }
    }
    __syncthreads();
    for (int i = threadIdx.x; i < NB; i += 256) {
      int c = hist[i];
      gbase[i] = (c > 0) ? atomicAdd(&cursor[i], c) : 0;
    }
    __syncthreads();
#pragma unroll
    for (int k = 0; k < EPB; k++) {
      if (bk[k] >= 0) {
        int pos = gbase[bk[k]] + rk[k];
        bins[(size_t)bk[k] * BCAP + pos] = pk[k];
      }
    }
    return;
  }

  // ---- gemm path (identical structure to proven gemm_mfma) ----
  short(*sA)[72] = (short(*)[72])smem;                  // X chunk bf16
  short(*sWl)[72] = (short(*)[72])(smem + 9216);        // Wl^T
  short(*sWr)[72] = (short(*)[72])(smem + 18432);       // Wr^T
  int gbid = (int)blockIdx.x - abk;
  int lane = threadIdx.x & 63, wv = threadIdx.x >> 6;
  int l15 = lane & 15, kq = lane >> 4;

  for (int i = threadIdx.x; i < 64 * 64; i += 256) {
    int k = i >> 6, j = i & 63;
    short vl = 0, vr = 0;
    if (k < K) {
      vl = (short)f2bf(Wl[k * 64 + j]);
      vr = (short)f2bf(Wr[k * 64 + j]);
    }
    sWl[j][k] = vl;
    sWr[j][k] = vr;
  }
  if (K < 64) {
    constexpr int PADW = (64 - K) / 2;
    for (int i = threadIdx.x; i < 64 * PADW; i += 256) {
      int row = i / PADW, p = i % PADW;
      *(unsigned*)&sA[row][K + 2 * p] = 0u;
    }
  }
  float bcol[4];
#pragma unroll
  for (int c = 0; c < 4; c++) bcol[c] = bias[c * 16 + l15];

  for (int nbase = gbid * 64; nbase < n_nodes; nbase += gemmb * 64) {
    __syncthreads();
    for (int i = threadIdx.x; i < 64 * (K / 4); i += 256) {
      int row = i / (K / 4), c4 = i % (K / 4);
      int rr = nbase + row;
      if (rr >= n_nodes) rr = n_nodes - 1;
      float4 xv = ((const float4*)(X + (size_t)rr * K))[c4];
      unsigned lo = ((unsigned)f2bf(xv.y) << 16) | (unsigned)f2bf(xv.x);
      unsigned hi = ((unsigned)f2bf(xv.w) << 16) | (unsigned)f2bf(xv.z);
      uint2 pk2 = {lo, hi};
      *(uint2*)&sA[row][c4 * 4] = pk2;
    }
    __syncthreads();

    float4v acc_t[4], acc_r[4];
#pragma unroll
    for (int c = 0; c < 4; c++) {
      acc_t[c] = (float4v){0.0f, 0.0f, 0.0f, 0.0f};
      acc_r[c] = (float4v){bcol[c], bcol[c], bcol[c], bcol[c]};
    }
#pragma unroll
    for (int s = 0; s < 2; s++) {
      short8v af = *(const short8v*)&sA[wv * 16 + l15][s * 32 + kq * 8];
#pragma unroll
      for (int c = 0; c < 4; c++) {
        short8v bl = *(const short8v*)&sWl[c * 16 + l15][s * 32 + kq * 8];
        short8v br = *(const short8v*)&sWr[c * 16 + l15][s * 32 + kq * 8];
        acc_t[c] = __builtin_amdgcn_mfma_f32_16x16x32_bf16(af, bl, acc_t[c], 0, 0, 0);
        acc_r[c] = __builtin_amdgcn_mfma_f32_16x16x32_bf16(af, br, acc_r[c], 0, 0, 0);
      }
    }
#pragma unroll
    for (int c = 0; c < 4; c++) {
      int j = c * 16 + l15;
#pragma unroll
      for (int g = 0; g < 4; g++) {
        int node = nbase + wv * 16 + kq * 4 + g;
        if (node < n_nodes) {
          t_out[(size_t)node * HH + j] = f2bf(acc_t[c][g]);
          r_out[(size_t)node * HH + j] = acc_r[c][g];
        }
      }
    }
  }
}

// build_csr with inline base computation: one 256-thread block per bucket.
// gb = sum_{i<b} cursor[i] (reduction over <=512 L2-hot ints), then local
// hist -> scan -> rp + csr scatter in the bucket's contiguous window.
__global__ __launch_bounds__(256) void build_csr2(
    const unsigned* __restrict__ bins, const int* __restrict__ cursor,
    int* __restrict__ rp, int* __restrict__ csr, int n_nodes, int E, int NB) {
  __shared__ int hist[BKT_SZ];
  __shared__ int aa[BKT_SZ], bb[BKT_SZ];
  __shared__ int cur[BKT_SZ];
  int b = blockIdx.x;
  int tid = threadIdx.x;
  int node0 = b << BKT_SHIFT;
  int cnt = cursor[b];
  const unsigned* bp = bins + (size_t)b * BCAP;

  // base = sum of counts of preceding buckets
  int part = 0;
  for (int i = tid; i < b; i += 256) part += cursor[i];
  aa[tid] = part;
  __syncthreads();
  for (int off = 128; off > 0; off >>= 1) {
    if (tid < off) aa[tid] += aa[tid + off];
    __syncthreads();
  }
  int gb = aa[0];
  __syncthreads();

  hist[tid] = 0;
  __syncthreads();
  for (int i = tid; i < cnt; i += 256) {
    atomicAdd(&hist[bp[i] >> 23], 1);
  }
  __syncthreads();
  int v = hist[tid];
  aa[tid] = v;
  __syncthreads();
  int* s = aa;
  int* d = bb;
  for (int off = 1; off < BKT_SZ; off <<= 1) {
    int t = s[tid] + ((tid >= off) ? s[tid - off] : 0);
    d[tid] = t;
    __syncthreads();
    int* tmp = s; s = d; d = tmp;
  }
  int loc = s[tid] - v;  // exclusive
  int node = node0 + tid;
  if (node < n_nodes) rp[node] = gb + loc;
  if (b == NB - 1 && tid == 0) rp[n_nodes] = E;
  cur[tid] = gb + loc;
  __syncthreads();
  for (int i = tid; i < cnt; i += 256) {
    unsigned p = bp[i];
    int dl = (int)(p >> 23);
    int pos = atomicAdd(&cur[dl], 1);
    csr[pos] = (int)(p & 0x7FFFFFu);
  }
}

// Standalone MFMA GEMM for layer 2 (same inner structure as fused path).
template <int K>
__global__ __launch_bounds__(256, 4) void gemm_mfma(
    const float* __restrict__ X, const float* __restrict__ Wl,
    const float* __restrict__ Wr, const float* __restrict__ bias,
    unsigned short* __restrict__ t_out, float* __restrict__ r_out,
    int n_nodes) {
  __shared__ short sA[64][72];
  __shared__ short sWl[64][72];
  __shared__ short sWr[64][72];
  int lane = threadIdx.x & 63, wv = threadIdx.x >> 6;
  int l15 = lane & 15, kq = lane >> 4;

  for (int i = threadIdx.x; i < 64 * 64; i += 256) {
    int k = i >> 6, j = i & 63;
    short vl = 0, vr = 0;
    if (k < K) {
      vl = (short)f2bf(Wl[k * 64 + j]);
      vr = (short)f2bf(Wr[k * 64 + j]);
    }
    sWl[j][k] = vl;
    sWr[j][k] = vr;
  }
  if (K < 64) {
    constexpr int PADW = (64 - K) / 2;
    for (int i = threadIdx.x; i < 64 * PADW; i += 256) {
      int row = i / PADW, p = i % PADW;
      *(unsigned*)&sA[row][K + 2 * p] = 0u;
    }
  }
  float bcol[4];
#pragma unroll
  for (int c = 0; c < 4; c++) bcol[c] = bias[c * 16 + l15];

  for (int nbase = blockIdx.x * 64; nbase < n_nodes; nbase += gridDim.x * 64) {
    __syncthreads();
    for (int i = threadIdx.x; i < 64 * (K / 4); i += 256) {
      int row = i / (K / 4), c4 = i % (K / 4);
      int rr = nbase + row;
      if (rr >= n_nodes) rr = n_nodes - 1;
      float4 xv = ((const float4*)(X + (size_t)rr * K))[c4];
      unsigned lo = ((unsigned)f2bf(xv.y) << 16) | (unsigned)f2bf(xv.x);
      unsigned hi = ((unsigned)f2bf(xv.w) << 16) | (unsigned)f2bf(xv.z);
      uint2 pk = {lo, hi};
      *(uint2*)&sA[row][c4 * 4] = pk;
    }
    __syncthreads();

    float4v acc_t[4], acc_r[4];
#pragma unroll
    for (int c = 0; c < 4; c++) {
      acc_t[c] = (float4v){0.0f, 0.0f, 0.0f, 0.0f};
      acc_r[c] = (float4v){bcol[c], bcol[c], bcol[c], bcol[c]};
    }
#pragma unroll
    for (int s = 0; s < 2; s++) {
      short8v af = *(const short8v*)&sA[wv * 16 + l15][s * 32 + kq * 8];
#pragma unroll
      for (int c = 0; c < 4; c++) {
        short8v bl = *(const short8v*)&sWl[c * 16 + l15][s * 32 + kq * 8];
        short8v br = *(const short8v*)&sWr[c * 16 + l15][s * 32 + kq * 8];
        acc_t[c] = __builtin_amdgcn_mfma_f32_16x16x32_bf16(af, bl, acc_t[c], 0, 0, 0);
        acc_r[c] = __builtin_amdgcn_mfma_f32_16x16x32_bf16(af, br, acc_r[c], 0, 0, 0);
      }
    }
#pragma unroll
    for (int c = 0; c < 4; c++) {
      int j = c * 16 + l15;
#pragma unroll
      for (int g = 0; g < 4; g++) {
        int node = nbase + wv * 16 + kq * 4 + g;
        if (node < n_nodes) {
          t_out[(size_t)node * HH + j] = f2bf(acc_t[c][g]);
          r_out[(size_t)node * HH + j] = acc_r[c][g];
        }
      }
    }
  }
}

// h[n] = sigmoid(mean(t[nbrs(n)]) + r[n]); t bf16 rows, r/h f32 rows.
// One 16-lane group per node (16 nodes/block); 8-deep unrolled gather.
__global__ __launch_bounds__(256) void agg_sig(
    const unsigned short* __restrict__ t, const float* __restrict__ r,
    const int* __restrict__ rp, const int* __restrict__ csr,
    float* __restrict__ h, int n_nodes) {
  int grp = threadIdx.x >> 4;
  int q = threadIdx.x & 15;
  int node = blockIdx.x * 16 + grp;
  if (node >= n_nodes) return;
  int rs = rp[node], re = rp[node + 1];
  int deg = re - rs;
  const uint2* tb = (const uint2*)t + q;

  float a0 = 0, a1 = 0, a2 = 0, a3 = 0;
  int j = rs;
  for (; j + 7 < re; j += 8) {
    uint2 u0 = tb[(size_t)csr[j + 0] * 16];
    uint2 u1 = tb[(size_t)csr[j + 1] * 16];
    uint2 u2 = tb[(size_t)csr[j + 2] * 16];
    uint2 u3 = tb[(size_t)csr[j + 3] * 16];
    uint2 u4 = tb[(size_t)csr[j + 4] * 16];
    uint2 u5 = tb[(size_t)csr[j + 5] * 16];
    uint2 u6 = tb[(size_t)csr[j + 6] * 16];
    uint2 u7 = tb[(size_t)csr[j + 7] * 16];
    a0 += ((bflo(u0.x) + bflo(u1.x)) + (bflo(u2.x) + bflo(u3.x))) +
          ((bflo(u4.x) + bflo(u5.x)) + (bflo(u6.x) + bflo(u7.x)));
    a1 += ((bfhi(u0.x) + bfhi(u1.x)) + (bfhi(u2.x) + bfhi(u3.x))) +
          ((bfhi(u4.x) + bfhi(u5.x)) + (bfhi(u6.x) + bfhi(u7.x)));
    a2 += ((bflo(u0.y) + bflo(u1.y)) + (bflo(u2.y) + bflo(u3.y))) +
          ((bflo(u4.y) + bflo(u5.y)) + (bflo(u6.y) + bflo(u7.y)));
    a3 += ((bfhi(u0.y) + bfhi(u1.y)) + (bfhi(u2.y) + bfhi(u3.y))) +
          ((bfhi(u4.y) + bfhi(u5.y)) + (bfhi(u6.y) + bfhi(u7.y)));
  }
  if (j + 3 < re) {
    uint2 u0 = tb[(size_t)csr[j + 0] * 16];
    uint2 u1 = tb[(size_t)csr[j + 1] * 16];
    uint2 u2 = tb[(size_t)csr[j + 2] * 16];
    uint2 u3 = tb[(size_t)csr[j + 3] * 16];
    a0 += (bflo(u0.x) + bflo(u1.x)) + (bflo(u2.x) + bflo(u3.x));
    a1 += (bfhi(u0.x) + bfhi(u1.x)) + (bfhi(u2.x) + bfhi(u3.x));
    a2 += (bflo(u0.y) + bflo(u1.y)) + (bflo(u2.y) + bflo(u3.y));
    a3 += (bfhi(u0.y) + bfhi(u1.y)) + (bfhi(u2.y) + bfhi(u3.y));
    j += 4;
  }
  for (; j < re; j++) {
    uint2 u = tb[(size_t)csr[j] * 16];
    a0 += bflo(u.x);
    a1 += bfhi(u.x);
    a2 += bflo(u.y);
    a3 += bfhi(u.y);
  }

  float inv = 1.0f / fmaxf((float)deg, 1.0f);
  float4 rv = ((const float4*)(r + (size_t)node * HH))[q];
  float4 o;
  o.x = sigmoidf_(a0 * inv + rv.x);
  o.y = sigmoidf_(a1 * inv + rv.y);
  o.z = sigmoidf_(a2 * inv + rv.z);
  o.w = sigmoidf_(a3 * inv + rv.w);
  ((float4*)(h + (size_t)node * HH))[q] = o;
}

// MLP head: h3 = sigmoid(h2 @ Wlin1 + blin1); out = softmax(h3 @ Wlin2 + blin2).
// 8 waves, 64-node chunk; lane holds Wlin1 column in registers (64 VGPR).
__global__ __launch_bounds__(512, 4) void head_k(
    const float* __restrict__ h2,
    const float* __restrict__ Wlin1, const float* __restrict__ blin1,
    const float* __restrict__ Wlin2, const float* __restrict__ blin2,
    float* __restrict__ out, int n_nodes) {
  __shared__ float sx[64][HH];
  __shared__ float sh3[64][HH];
  __shared__ float sw2[HH * 2];
  int wv = threadIdx.x >> 6, lane = threadIdx.x & 63;

  float w1[HH];
#pragma unroll
  for (int k = 0; k < HH; k++) w1[k] = Wlin1[k * HH + lane];
  float bv = blin1[lane];
  if (threadIdx.x < HH * 2) sw2[threadIdx.x] = Wlin2[threadIdx.x];
  float sb20 = blin2[0], sb21 = blin2[1];

  for (int nbase = blockIdx.x * 64; nbase < n_nodes; nbase += gridDim.x * 64) {
    __syncthreads();
    for (int i = threadIdx.x; i < 64 * (HH / 4); i += 512) {
      int row = i >> 4, c4 = i & 15;
      int rr = nbase + row;
      if (rr >= n_nodes) rr = n_nodes - 1;
      ((float4*)sx[row])[c4] = ((const float4*)(h2 + (size_t)rr * HH))[c4];
    }
    __syncthreads();

    float acc[8];
#pragma unroll
    for (int m = 0; m < 8; m++) acc[m] = bv;
#pragma unroll
    for (int k = 0; k < HH; k += 4) {
#pragma unroll
      for (int m = 0; m < 8; m++) {
        float4 a = *(const float4*)&sx[wv * 8 + m][k];
        acc[m] += a.x * w1[k] + a.y * w1[k + 1] + a.z * w1[k + 2] + a.w * w1[k + 3];
      }
    }
#pragma unroll
    for (int m = 0; m < 8; m++) sh3[wv * 8 + m][lane] = sigmoidf_(acc[m]);
    __syncthreads();

    int node_l = threadIdx.x >> 3;
    int sub = threadIdx.x & 7;
    float l0 = 0.0f, l1 = 0.0f;
#pragma unroll
    for (int kk = 0; kk < 8; kk++) {
      int k = sub * 8 + kk;
      float v = sh3[node_l][k];
      l0 += v * sw2[k * 2 + 0];
      l1 += v * sw2[k * 2 + 1];
    }
    l0 += __shfl_xor(l0, 1); l1 += __shfl_xor(l1, 1);
    l0 += __shfl_xor(l0, 2); l1 += __shfl_xor(l1, 2);
    l0 += __shfl_xor(l0, 4); l1 += __shfl_xor(l1, 4);
    int node = nbase + node_l;
    if (sub == 0 && node < n_nodes) {
      l0 += sb20;
      l1 += sb21;
      float mx = fmaxf(l0, l1);
      float p0 = __expf(l0 - mx), p1 = __expf(l1 - mx);
      float s = 1.0f / (p0 + p1);
      float2 o2 = {p0 * s, p1 * s};
      ((float2*)out)[node] = o2;
    }
  }
}

extern "C" void kernel_launch(void* const* d_in, const int* in_sizes, int n_in,
                              void* d_out, int out_size, void* d_ws, size_t ws_size,
                              hipStream_t stream) {
  const float* x     = (const float*)d_in[0];
  const int*   ei    = (const int*)d_in[1];
  const float* W1l   = (const float*)d_in[2];
  const float* b1l   = (const float*)d_in[3];
  const float* W1r   = (const float*)d_in[4];
  const float* W2l   = (const float*)d_in[5];
  const float* b2l   = (const float*)d_in[6];
  const float* W2r   = (const float*)d_in[7];
  const float* Wlin1 = (const float*)d_in[8];
  const float* blin1 = (const float*)d_in[9];
  const float* Wlin2 = (const float*)d_in[10];
  const float* blin2 = (const float*)d_in[11];
  float* out = (float*)d_out;

  int n = in_sizes[0] / NF1;
  int E = in_sizes[1] / 2;
  int NB = (n + BKT_SZ - 1) >> BKT_SHIFT;  // 391 (<= 512)

  int* cursor = (int*)d_ws;                 // [NB]
  int* rp     = cursor + NB;                // [n+1]
  int* csr    = rp + n + 1;                 // [E]
  size_t off = (size_t)(NB + n + 1 + E) * sizeof(int);
  off = (off + 255) & ~(size_t)255;
  unsigned short* tbuf = (unsigned short*)((char*)d_ws + off);  // [n,64] bf16
  off += (size_t)n * HH * sizeof(unsigned short);
  off = (off + 255) & ~(size_t)255;
  float* rbuf = (float*)((char*)d_ws + off);  // [n,64] f32
  off += (size_t)n * HH * sizeof(float);
  off = (off + 255) & ~(size_t)255;
  float* hbuf = (float*)((char*)d_ws + off);  // [n,64] f32 (h1, then h2)
  // bins aliases hbuf: NB*BCAP*4 = 7.5MB <= n*64*4 = 25.6MB; bins is dead
  // after build_csr2, and hbuf is first written by agg1 (after build_csr2).
  unsigned* bins = (unsigned*)hbuf;

  hipMemsetAsync(cursor, 0, (size_t)NB * sizeof(int), stream);

  int abk = (E + 256 * EPB - 1) / (256 * EPB);   // 391
  int gemmb = (n + 63) / 64;
  if (gemmb > 1024) gemmb = 1024;
  int aggb = (n + 15) / 16;
  int headb = (n + 63) / 64;
  if (headb > 1024) headb = 1024;

  // fused: bin_edges (blocks [0,abk)) || layer-1 GEMM (blocks [abk, abk+gemmb))
  fused_bin_gemm<NF1><<<abk + gemmb, 256, 0, stream>>>(
      ei, cursor, bins, E, NB, x, W1l, W1r, b1l, tbuf, rbuf, n, abk, gemmb);

  build_csr2<<<NB, 256, 0, stream>>>(bins, cursor, rp, csr, n, E, NB);

  // layer 1 aggregation: h1 = sigmoid(mean(t)+r)  (overwrites bins region)
  agg_sig<<<aggb, 256, 0, stream>>>(tbuf, rbuf, rp, csr, hbuf, n);

  // layer 2: t = h1@W2l (bf16), r = h1@W2r + b2l; h2 = sigmoid(mean(t)+r)
  gemm_mfma<HH><<<gemmb, 256, 0, stream>>>(hbuf, W2l, W2r, b2l, tbuf, rbuf, n);
  agg_sig<<<aggb, 256, 0, stream>>>(tbuf, rbuf, rp, csr, hbuf, n);

  // MLP head
  head_k<<<headb, 512, 0, stream>>>(hbuf, Wlin1, blin1, Wlin2, blin2, out, n);
}